// Round 9
// baseline (7347.802 us; speedup 1.0000x reference)
//
#include <hip/hip_runtime.h>
#include <math.h>

// Problem dims
#define T_ 128
#define B_ 512
#define N_ 256
#define M_ 512
#define G_ 2048   // 4*M
#define NBLK 256  // 8 groups x 32 blocks, 1 block/CU, 1024 threads = 16 waves/CU
#define GSZ 32    // blocks per group
#define KC_ 24    // K chunks of 32 (768 total: 256 x-tilde + 512 h)

typedef unsigned long long ull;
typedef __attribute__((ext_vector_type(8))) short short8v;
typedef __attribute__((ext_vector_type(4))) float float4v;

// ---------------------------------------------------------------------------
// Device-coherent access, relaxed (sc1): no cache flush, cross-XCD safe
// ---------------------------------------------------------------------------
__device__ __forceinline__ float ld_dev(const float* p) {
    return __hip_atomic_load(const_cast<float*>(p), __ATOMIC_RELAXED,
                             __HIP_MEMORY_SCOPE_AGENT);
}
__device__ __forceinline__ void st_dev(float* p, float v) {
    __hip_atomic_store(p, v, __ATOMIC_RELAXED, __HIP_MEMORY_SCOPE_AGENT);
}
__device__ __forceinline__ ull ld_dev64(const ull* p) {
    return __hip_atomic_load(const_cast<ull*>(p), __ATOMIC_RELAXED,
                             __HIP_MEMORY_SCOPE_AGENT);
}
__device__ __forceinline__ void st_dev64(ull* p, ull v) {
    __hip_atomic_store(p, v, __ATOMIC_RELAXED, __HIP_MEMORY_SCOPE_AGENT);
}

// Fast transcendentals (abs err ~1e-6, threshold 1e-3)
__device__ __forceinline__ float fast_tanh(float x) {
    float e = __expf(2.f * x);
    return 1.f - __fdividef(2.f, e + 1.f);
}
__device__ __forceinline__ float fast_sig(float x) {
    return __fdividef(1.f, 1.f + __expf(-x));
}

// bf16 helpers (RNE)
__device__ __forceinline__ unsigned short bf16_rne(float f) {
    unsigned u = __float_as_uint(f);
    return (unsigned short)((u + 0x7FFFu + ((u >> 16) & 1u)) >> 16);
}
__device__ __forceinline__ float bf16_tof(unsigned short h) {
    return __uint_as_float(((unsigned)h) << 16);
}
__device__ __forceinline__ ull pack4(const unsigned short* s) {
    return (ull)s[0] | ((ull)s[1] << 16) | ((ull)s[2] << 32) | ((ull)s[3] << 48);
}

// ---------------------------------------------------------------------------
// Group barrier: 32 blocks, relaxed ticket, no L2 flush.
// ---------------------------------------------------------------------------
__device__ __forceinline__ void group_bar(int* gbar, int goal) {
    __syncthreads();
    if (threadIdx.x == 0) {
        asm volatile("s_waitcnt vmcnt(0)" ::: "memory");
        __hip_atomic_fetch_add(gbar, 1, __ATOMIC_RELAXED,
                               __HIP_MEMORY_SCOPE_AGENT);
        while (__hip_atomic_load(gbar, __ATOMIC_RELAXED,
                                 __HIP_MEMORY_SCOPE_AGENT) < goal) {
            __builtin_amdgcn_s_sleep(1);
        }
    }
    __syncthreads();
}

// ---------------------------------------------------------------------------
// Prep: fused bias bg[4m+g] = b_ih[g*512+m] + b_hh[g*512+m]
// ---------------------------------------------------------------------------
__global__ __launch_bounds__(256) void prep_bg(
    const float* __restrict__ bih, const float* __restrict__ bhh,
    float* __restrict__ bg)
{
    int rp = blockIdx.x * 256 + threadIdx.x;
    if (rp < 2048) {
        int m = rp >> 2, g = rp & 3;
        int row = g * 512 + m;
        bg[rp] = bih[row] + bhh[row];
    }
}

// ---------------------------------------------------------------------------
// Prep: Wt fragment-tiled bf16 hi/lo planes.
// ---------------------------------------------------------------------------
__global__ __launch_bounds__(256) void prep_wt(
    const float* __restrict__ Wih, const float* __restrict__ Whh,
    uint4* __restrict__ Wt_hi, uint4* __restrict__ Wt_lo)
{
    int uid = blockIdx.x * 256 + threadIdx.x;   // < 196608
    int ct = uid / (KC_ * 64);
    int rem = uid % (KC_ * 64);
    int kc = rem >> 6, lane = rem & 63;
    int col = ct * 16 + (lane & 15);
    int m = col >> 2, gi = col & 3;
    int grow = gi * 512 + m;
    int quad = lane >> 4;
    union { unsigned short s[8]; uint4 v; } hi, lo;
#pragma unroll
    for (int j = 0; j < 8; j++) {
        int k = kc * 32 + quad * 8 + j;
        float v = (k < 256) ? Wih[(size_t)grow * 256 + k]
                            : Whh[(size_t)grow * 512 + (k - 256)];
        hi.s[j] = bf16_rne(v);
        lo.s[j] = bf16_rne(v - bf16_tof(hi.s[j]));
    }
    Wt_hi[uid] = hi.v;
    Wt_lo[uid] = lo.v;
}

// We_p[q][s][j] = We_w[s][q*4+j]
__global__ __launch_bounds__(256) void prep_wep(
    const float* __restrict__ We_w, float* __restrict__ We_p)
{
    int idx = blockIdx.x * 256 + threadIdx.x;   // < 131072
    int q = idx >> 9, rest = idx & 511, s = rest >> 2, j = rest & 3;
    We_p[idx] = We_w[s * 1024 + q * 4 + j];
}

// ---------------------------------------------------------------------------
// Precompute Ue_x + Ue_b, packed bf16 s-pairs:
// ue_pk[(b*64 + s/2)*256 + n] = bf16(ue[b][s][n]) | bf16(ue[b][s+1][n])<<16
// ---------------------------------------------------------------------------
__global__ __launch_bounds__(256) void ue_pre(
    const float* __restrict__ x, const float* __restrict__ Ue_w,
    const float* __restrict__ Ue_b, unsigned* __restrict__ ue_pk)
{
    const int b = blockIdx.y;
    const int s0 = blockIdx.x * 32;
    const int n = threadIdx.x;
    __shared__ float xs[32][256];
    __shared__ float uws[32][32];

    float acc[32];
#pragma unroll
    for (int i = 0; i < 32; i++) acc[i] = 0.f;

#pragma unroll 1
    for (int tc = 0; tc < 4; tc++) {
        __syncthreads();
#pragma unroll
        for (int tt = 0; tt < 32; tt++)
            xs[tt][n] = x[(size_t)(tc * 32 + tt) * (B_ * N_) + b * N_ + n];
#pragma unroll
        for (int q = 0; q < 4; q++) {
            int e = q * 256 + n;
            int s = e >> 5, tt = e & 31;
            uws[s][tt] = Ue_w[(s0 + s) * T_ + tc * 32 + tt];
        }
        __syncthreads();
        float xr[32];
#pragma unroll
        for (int tt = 0; tt < 32; tt++) xr[tt] = xs[tt][n];
#pragma unroll
        for (int s = 0; s < 32; s++) {
            float a = acc[s];
#pragma unroll
            for (int tt = 0; tt < 32; tt++) a += xr[tt] * uws[s][tt];
            acc[s] = a;
        }
    }
#pragma unroll
    for (int i = 0; i < 16; i++) {
        float v0 = acc[2 * i] + Ue_b[s0 + 2 * i];
        float v1 = acc[2 * i + 1] + Ue_b[s0 + 2 * i + 1];
        unsigned pk = (unsigned)bf16_rne(v0) | ((unsigned)bf16_rne(v1) << 16);
        ue_pk[((size_t)b * 64 + (s0 >> 1) + i) * 256 + n] = pk;
    }
}

// ---------------------------------------------------------------------------
// Persistent scan. 1024 thr/block = 16 waves/CU. ue in 32 VGPRs/thread
// (2 threads per (b,n), s split 2-way). 
// Part A: we-GEMM (8-way K-split) + register attention (shuffle softmax)
//         + At emit (bf16 hi/lo fragment-tiled).
// Part C: MFMA gates GEMM, 16 waves = 8 tile-sets x 2 kc-halves, LDS
//         partial-reduce, fused LSTM cell.
// ---------------------------------------------------------------------------
__global__ __launch_bounds__(1024, 4) void scan_persist(
    const float* __restrict__ x, const float* __restrict__ h0,
    const float* __restrict__ We_p, const float* __restrict__ We_b,
    const float* __restrict__ ve_w, const unsigned* __restrict__ ue_pk,
    const short8v* __restrict__ Wt_hi, const short8v* __restrict__ Wt_lo,
    const float* __restrict__ bg,
    float* __restrict__ cbuf, float* __restrict__ hseq,
    ull* __restrict__ At_hi, ull* __restrict__ At_lo, int* bar)
{
    const int tid = threadIdx.x;
    const int blk = blockIdx.x;
    const int g = blk >> 5;          // group 0..7
    const int sg = blk & 31;         // slot in group
    int* gbar = bar + g * 32;

    __shared__ __align__(16) float hcA[1024];
    __shared__ __align__(16) float hcB[1024];
    __shared__ float wepartA[1024];
    __shared__ float wepartB[1024];
    __shared__ __align__(16) float wv[2][256];   // [half][s*2+{we,ve}]
    __shared__ __align__(16) float ep[4][256];   // [half*2+shalf][n]
    __shared__ float red[16];
    __shared__ float xs[2][256];
    __shared__ float gates_s[64][65];
    __shared__ float credbuf[8][64][9];          // pad 9: conflict-free

    // part A ids
    const int bA = g * 64 + sg * 2;
    const int bB = bA + 1;
    const int s_ = tid & 127;        // we-GEMM s
    const int kslice = tid >> 7;     // we-GEMM K-slice 0..7
    const int halfb = tid >> 9;      // attention batch half
    const int shalf = (tid >> 8) & 1;// attention s half
    const int tt = tid & 255;        // attention n
    // part C ids
    const int lane = tid & 63;
    const int w2 = tid >> 6;         // wave 0..15
    const int iC = w2 & 7;
    const int khalf = w2 >> 3;       // kc half
    const int rtC = g * 4 + (iC & 3);
    const int ctA = sg * 4 + (iC >> 2) * 2;
    const int ctB = ctA + 1;
    const int quad = lane >> 4;

    if (tid < 128) {
        float v = ve_w[tid];
        wv[0][tid * 2 + 1] = v;      // ve entries constant across t
        wv[1][tid * 2 + 1] = v;
    }

    // ---- one-time: load this thread's ue slice (32 s-pairs) into VGPRs ----
    unsigned ureg[32];
    {
        const unsigned* up = ue_pk
            + ((size_t)(bA + halfb) * 64 + shalf * 32) * 256 + tt;
#pragma unroll
        for (int i = 0; i < 32; i++) ureg[i] = up[(size_t)i * 256];
    }

#pragma unroll 1
    for (int t = 0; t < T_; t++) {
        const float* hprev = t ? (hseq + (size_t)(t - 1) * (B_ * M_)) : h0;

        // ---------------- Part A ----------------
        {
            hcA[tid] = (tid < 512) ? ld_dev(hprev + bA * M_ + tid)
                                   : ld_dev(cbuf + bA * M_ + tid - 512);
            hcB[tid] = (tid < 512) ? ld_dev(hprev + bB * M_ + tid)
                                   : ld_dev(cbuf + bB * M_ + tid - 512);
            __syncthreads();

            // we partials: 8-way K split, shared We_p stream
            float accA = 0.f, accB = 0.f;
            const float4* wp4 = (const float4*)We_p;
#pragma unroll 4
            for (int q = kslice * 32; q < kslice * 32 + 32; q++) {
                float4 wq = wp4[q * 128 + s_];
                float4 a = *(const float4*)&hcA[q * 4];
                float4 b2 = *(const float4*)&hcB[q * 4];
                accA += wq.x * a.x + wq.y * a.y + wq.z * a.z + wq.w * a.w;
                accB += wq.x * b2.x + wq.y * b2.y + wq.z * b2.z + wq.w * b2.w;
            }
            wepartA[tid] = accA;
            wepartB[tid] = accB;
            __syncthreads();
            if (tid < 256) {
                int b2 = tid >> 7, s = tid & 127;
                const float* wp = b2 ? wepartB : wepartA;
                float sum = 0.f;
#pragma unroll
                for (int ks = 0; ks < 8; ks++) sum += wp[ks * 128 + s];
                wv[b2][s * 2] = sum + We_b[s];
            }
            __syncthreads();

            // attention partial: ue from registers, we/ve from LDS
            float epart = 0.f;
#pragma unroll
            for (int ii = 0; ii < 32; ii++) {
                unsigned u = ureg[ii];
                float u0 = __uint_as_float(u << 16);
                float u1 = __uint_as_float(u & 0xFFFF0000u);
                float4 q = *(const float4*)&wv[halfb][(shalf * 32 + ii) * 4];
                epart += fast_tanh(q.x + u0) * q.y;
                epart += fast_tanh(q.z + u1) * q.w;
            }
            ep[halfb * 2 + shalf][tt] = epart;
            __syncthreads();

            // softmax over n (256) per half, via wave shuffles
            float e = 0.f, ex = 0.f;
            if (tid < 512) {
                int hh = tid >> 8, n = tid & 255;
                e = ep[hh * 2][n] + ep[hh * 2 + 1][n];
                float m = e;
#pragma unroll
                for (int off = 32; off > 0; off >>= 1)
                    m = fmaxf(m, __shfl_xor(m, off));
                if ((tid & 63) == 0) red[tid >> 6] = m;
            }
            __syncthreads();
            if (tid < 512) {
                int hh = tid >> 8;
                float mx = fmaxf(fmaxf(red[hh * 4 + 0], red[hh * 4 + 1]),
                                 fmaxf(red[hh * 4 + 2], red[hh * 4 + 3]));
                ex = __expf(e - mx);
                float s2 = ex;
#pragma unroll
                for (int off = 32; off > 0; off >>= 1)
                    s2 += __shfl_xor(s2, off);
                if ((tid & 63) == 0) red[8 + (tid >> 6)] = s2;
            }
            __syncthreads();
            if (tid < 512) {
                int hh = tid >> 8, n = tid & 255;
                float denom = red[8 + hh * 4 + 0] + red[8 + hh * 4 + 1]
                            + red[8 + hh * 4 + 2] + red[8 + hh * 4 + 3];
                float alpha = __fdividef(ex, denom);
                xs[hh][n] = alpha * x[(size_t)t * (B_ * N_) + (bA + hh) * N_ + n];
            }
            __syncthreads();

            // ---- emit tiled bf16 hi/lo: h(t-1) (128 units) + x~(t) (64) ----
            if (tid < 192) {
                int rowsel, kc, qd;
                float v[8];
                if (tid < 128) {                 // h region, kc 8..23
                    rowsel = tid >> 6;
                    int q2 = tid & 63;
                    kc = 8 + (q2 >> 2); qd = q2 & 3;
                    const float* hcX = rowsel ? hcB : hcA;
                    int mb = (kc - 8) * 32 + qd * 8;
#pragma unroll
                    for (int j = 0; j < 8; j++) v[j] = hcX[mb + j];
                } else {                         // x~ region, kc 0..7
                    int u2 = tid - 128;
                    rowsel = u2 >> 5;
                    int q2 = u2 & 31;
                    kc = q2 >> 2; qd = q2 & 3;
                    int nb = kc * 32 + qd * 8;
#pragma unroll
                    for (int j = 0; j < 8; j++) v[j] = xs[rowsel][nb + j];
                }
                int b2 = bA + rowsel;
                int rt = b2 >> 4;
                int ln = qd * 16 + (b2 & 15);
                size_t uidx = ((size_t)(rt * KC_ + kc) * 64 + ln) * 2; // ull idx
                unsigned short hi[8], lo[8];
#pragma unroll
                for (int j = 0; j < 8; j++) {
                    hi[j] = bf16_rne(v[j]);
                    lo[j] = bf16_rne(v[j] - bf16_tof(hi[j]));
                }
                st_dev64(At_hi + uidx,     pack4(hi));
                st_dev64(At_hi + uidx + 1, pack4(hi + 4));
                st_dev64(At_lo + uidx,     pack4(lo));
                st_dev64(At_lo + uidx + 1, pack4(lo + 4));
            }
        }
        group_bar(gbar, (t * 2 + 1) * GSZ);

        // -------- Part C: MFMA gates GEMM (kc-split-2) + fused cell --------
        {
            float4v acc0 = {0.f, 0.f, 0.f, 0.f};
            float4v acc1 = {0.f, 0.f, 0.f, 0.f};
            const int kc0 = khalf * 12;

            size_t aidx = ((size_t)(rtC * KC_ + kc0) * 64 + lane) * 2;
            ull pah0 = ld_dev64(At_hi + aidx), pah1 = ld_dev64(At_hi + aidx + 1);
            ull pal0 = ld_dev64(At_lo + aidx), pal1 = ld_dev64(At_lo + aidx + 1);
            short8v pw0h = Wt_hi[(ctA * KC_ + kc0) * 64 + lane];
            short8v pw0l = Wt_lo[(ctA * KC_ + kc0) * 64 + lane];
            short8v pw1h = Wt_hi[(ctB * KC_ + kc0) * 64 + lane];
            short8v pw1l = Wt_lo[(ctB * KC_ + kc0) * 64 + lane];

#pragma unroll 1
            for (int kc = kc0; kc < kc0 + 12; kc++) {
                ull ah0 = pah0, ah1 = pah1, al0 = pal0, al1 = pal1;
                short8v w0h = pw0h, w0l = pw0l, w1h = pw1h, w1l = pw1l;
                if (kc + 1 < kc0 + 12) {
                    size_t ai = ((size_t)(rtC * KC_ + kc + 1) * 64 + lane) * 2;
                    pah0 = ld_dev64(At_hi + ai); pah1 = ld_dev64(At_hi + ai + 1);
                    pal0 = ld_dev64(At_lo + ai); pal1 = ld_dev64(At_lo + ai + 1);
                    pw0h = Wt_hi[(ctA * KC_ + kc + 1) * 64 + lane];
                    pw0l = Wt_lo[(ctA * KC_ + kc + 1) * 64 + lane];
                    pw1h = Wt_hi[(ctB * KC_ + kc + 1) * 64 + lane];
                    pw1l = Wt_lo[(ctB * KC_ + kc + 1) * 64 + lane];
                }
                union { ull u[2]; short8v s; } aH, aL;
                aH.u[0] = ah0; aH.u[1] = ah1;
                aL.u[0] = al0; aL.u[1] = al1;
                acc0 = __builtin_amdgcn_mfma_f32_16x16x32_bf16(aH.s, w0h, acc0, 0, 0, 0);
                acc1 = __builtin_amdgcn_mfma_f32_16x16x32_bf16(aH.s, w1h, acc1, 0, 0, 0);
                acc0 = __builtin_amdgcn_mfma_f32_16x16x32_bf16(aH.s, w0l, acc0, 0, 0, 0);
                acc1 = __builtin_amdgcn_mfma_f32_16x16x32_bf16(aH.s, w1l, acc1, 0, 0, 0);
                acc0 = __builtin_amdgcn_mfma_f32_16x16x32_bf16(aL.s, w0h, acc0, 0, 0, 0);
                acc1 = __builtin_amdgcn_mfma_f32_16x16x32_bf16(aL.s, w1h, acc1, 0, 0, 0);
            }

            // kc-half reduction via LDS
            if (khalf == 1) {
#pragma unroll
                for (int r = 0; r < 4; r++) {
                    credbuf[iC][lane][r] = acc0[r];
                    credbuf[iC][lane][4 + r] = acc1[r];
                }
            }
            __syncthreads();
            if (khalf == 0) {
#pragma unroll
                for (int r = 0; r < 4; r++) {
                    acc0[r] += credbuf[iC][lane][r];
                    acc1[r] += credbuf[iC][lane][4 + r];
                }
                // dump C/D (col=lane&15, row=quad*4+reg) into gates tile
                const int r0 = (iC & 3) * 16;
                const int c0l = (iC >> 2) * 32;
#pragma unroll
                for (int r = 0; r < 4; r++) {
                    gates_s[r0 + quad * 4 + r][c0l + (lane & 15)] = acc0[r];
                    gates_s[r0 + quad * 4 + r][c0l + 16 + (lane & 15)] = acc1[r];
                }
            }
            __syncthreads();

            // fused cell: 1024 cells (64 b x 16 m), 1 per thread
            float* hseq_t = hseq + (size_t)t * (B_ * M_);
            {
                int b_l = tid >> 4, mi = tid & 15;
                float gi = gates_s[b_l][mi * 4 + 0] + bg[sg * 64 + mi * 4 + 0];
                float gf = gates_s[b_l][mi * 4 + 1] + bg[sg * 64 + mi * 4 + 1];
                float gc = gates_s[b_l][mi * 4 + 2] + bg[sg * 64 + mi * 4 + 2];
                float go = gates_s[b_l][mi * 4 + 3] + bg[sg * 64 + mi * 4 + 3];
                int idx = (g * 64 + b_l) * M_ + sg * 16 + mi;
                float cn = fast_sig(gf) * ld_dev(&cbuf[idx])
                         + fast_sig(gi) * fast_tanh(gc);
                st_dev(&cbuf[idx], cn);
                st_dev(&hseq_t[idx], fast_sig(go) * fast_tanh(cn));
            }
        }
        group_bar(gbar, (t * 2 + 2) * GSZ);
    }
}

// ---------------------------------------------------------------------------
// Post: l[b,t] += sum_m tanh(h_seq@Ud_w^T + Ud_b)*vd_w   (rows=T*B, cols=M)
// ---------------------------------------------------------------------------
__global__ __launch_bounds__(256) void gemm_l(
    const float* __restrict__ A1,
    const float* __restrict__ W1,
    const float* __restrict__ bias1,
    const float* __restrict__ vw, float* __restrict__ lout)
{
    __shared__ float As[16][68];
    __shared__ float Ws[16][68];
    __shared__ float rsum[64];

    const int tid = threadIdx.x;
    const int tx = tid & 15, ty = tid >> 4;
    const int row0 = blockIdx.y * 64;
    const int col0 = blockIdx.x * 64;
    const int li = tid >> 2;
    const int lk4 = (tid & 3) * 4;

    float acc[4][4];
#pragma unroll
    for (int r = 0; r < 4; r++)
#pragma unroll
        for (int cc = 0; cc < 4; cc++) acc[r][cc] = 0.f;

    float4 av = *(const float4*)&A1[(size_t)(row0 + li) * M_ + lk4];
    float4 wvv = *(const float4*)&W1[(size_t)(col0 + li) * M_ + lk4];
#pragma unroll 1
    for (int kk = 0; kk < 512; kk += 16) {
        __syncthreads();
        As[lk4 + 0][li] = av.x; As[lk4 + 1][li] = av.y;
        As[lk4 + 2][li] = av.z; As[lk4 + 3][li] = av.w;
        Ws[lk4 + 0][li] = wvv.x; Ws[lk4 + 1][li] = wvv.y;
        Ws[lk4 + 2][li] = wvv.z; Ws[lk4 + 3][li] = wvv.w;
        __syncthreads();
        if (kk + 16 < 512) {
            av = *(const float4*)&A1[(size_t)(row0 + li) * M_ + kk + 16 + lk4];
            wvv = *(const float4*)&W1[(size_t)(col0 + li) * M_ + kk + 16 + lk4];
        }
#pragma unroll
        for (int k = 0; k < 16; k++) {
            float4 a = *(const float4*)&As[k][ty * 4];
            float4 w2 = *(const float4*)&Ws[k][tx * 4];
            acc[0][0] += a.x * w2.x; acc[0][1] += a.x * w2.y;
            acc[0][2] += a.x * w2.z; acc[0][3] += a.x * w2.w;
            acc[1][0] += a.y * w2.x; acc[1][1] += a.y * w2.y;
            acc[1][2] += a.y * w2.z; acc[1][3] += a.y * w2.w;
            acc[2][0] += a.z * w2.x; acc[2][1] += a.z * w2.y;
            acc[2][2] += a.z * w2.z; acc[2][3] += a.z * w2.w;
            acc[3][0] += a.w * w2.x; acc[3][1] += a.w * w2.y;
            acc[3][2] += a.w * w2.z; acc[3][3] += a.w * w2.w;
        }
    }

    __syncthreads();
    if (tid < 64) rsum[tid] = 0.f;
    __syncthreads();
    float part[4] = {0.f, 0.f, 0.f, 0.f};
#pragma unroll
    for (int r = 0; r < 4; r++)
#pragma unroll
        for (int cc = 0; cc < 4; cc++) {
            int gc = col0 + tx * 4 + cc;
            part[r] += fast_tanh(acc[r][cc] + bias1[gc]) * vw[gc];
        }
#pragma unroll
    for (int r = 0; r < 4; r++)
        atomicAdd(&rsum[ty * 4 + r], part[r]);
    __syncthreads();
    if (tid < 64) {
        int gr = row0 + tid;          // gr = t*512 + b
        int b = gr & 511, t = gr >> 9;
        atomicAdd(&lout[b * 128 + t], rsum[tid]);
    }
}

// ---------------------------------------------------------------------------
// Final: beta = softmax_t(l); ctx = sum_t beta*h_seq; logits = ctx.out_w+out_b
// ---------------------------------------------------------------------------
__global__ __launch_bounds__(512) void final_kernel(
    const float* __restrict__ lbuf, const float* __restrict__ hseq,
    const float* __restrict__ out_w, const float* __restrict__ out_b,
    float* __restrict__ out)
{
    const int b = blockIdx.x;
    const int tid = threadIdx.x;
    __shared__ float beta_s[128];
    __shared__ float red[512];

    float lv = (tid < 128) ? lbuf[b * 128 + tid] : -1e30f;
    red[tid] = lv; __syncthreads();
    for (int off = 256; off >= 1; off >>= 1) {
        if (tid < off) red[tid] = fmaxf(red[tid], red[tid + off]);
        __syncthreads();
    }
    float mx = red[0]; __syncthreads();
    float ex = (tid < 128) ? __expf(lv - mx) : 0.f;
    red[tid] = ex; __syncthreads();
    for (int off = 256; off >= 1; off >>= 1) {
        if (tid < off) red[tid] += red[tid + off];
        __syncthreads();
    }
    float denom = red[0];
    if (tid < 128) {
        float bt = ex / denom;
        beta_s[tid] = bt;
        out[512 + b * 128 + tid] = bt;
    }
    __syncthreads();

    float ctx = 0.f;
#pragma unroll 4
    for (int t = 0; t < 128; t++)
        ctx += beta_s[t] * hseq[(size_t)t * (B_ * M_) + b * M_ + tid];

    red[tid] = ctx * out_w[tid]; __syncthreads();
    for (int off = 256; off >= 1; off >>= 1) {
        if (tid < off) red[tid] += red[tid + off];
        __syncthreads();
    }
    if (tid == 0) out[b] = red[0] + out_b[0];
}

// ---------------------------------------------------------------------------
extern "C" void kernel_launch(void* const* d_in, const int* in_sizes, int n_in,
                              void* d_out, int out_size, void* d_ws, size_t ws_size,
                              hipStream_t stream)
{
    const float* x    = (const float*)d_in[0];
    const float* h0   = (const float*)d_in[1];
    const float* c0   = (const float*)d_in[2];
    const float* Wih  = (const float*)d_in[3];
    const float* Whh  = (const float*)d_in[4];
    const float* b_ih = (const float*)d_in[5];
    const float* b_hh = (const float*)d_in[6];
    const float* We_w = (const float*)d_in[7];
    const float* We_b = (const float*)d_in[8];
    const float* Ue_w = (const float*)d_in[9];
    const float* Ue_b = (const float*)d_in[10];
    const float* ve_w = (const float*)d_in[11];
    const float* Ud_w = (const float*)d_in[13];
    const float* Ud_b = (const float*)d_in[14];
    const float* vd_w = (const float*)d_in[15];
    const float* out_w = (const float*)d_in[17];
    const float* out_b = (const float*)d_in[18];
    float* out = (float*)d_out;

    // workspace layout (float slots). lbuf aliases ue_pk (disjoint lifetimes).
    float* ws    = (float*)d_ws;
    float* ue_pk = ws;                       //  8,388,608  (B*64*N uints) [scan]
    float* lbuf  = ws;                       //     65,536  (B*T)   [post only]
    float* hseq  = ue_pk + 8388608;          // 33,554,432  (T*B*M)
    float* cbuf  = hseq + 33554432;          //    262,144  (B*M)
    float* We_p  = cbuf + 262144;            //    131,072
    float* bgv   = We_p + 131072;            //      2,048
    float* At_hi = bgv + 2048;               //    196,608  (32*24*64*8 bf16)
    float* At_lo = At_hi + 196608;           //    196,608
    float* Wt_hi = At_lo + 196608;           //    786,432  (128*24*64*8 bf16)
    float* Wt_lo = Wt_hi + 786432;           //    786,432
    int*   bar   = (int*)(Wt_lo + 786432);   //   8*32 ints

    hipMemcpyAsync(cbuf, c0, (size_t)B_ * M_ * 4, hipMemcpyDeviceToDevice, stream);
    hipMemsetAsync(bar, 0, 8 * 32 * 4, stream);

    prep_bg<<<8, 256, 0, stream>>>(b_ih, b_hh, bgv);
    prep_wt<<<768, 256, 0, stream>>>(Wih, Whh, (uint4*)Wt_hi, (uint4*)Wt_lo);
    prep_wep<<<512, 256, 0, stream>>>(We_w, We_p);
    ue_pre<<<dim3(4, 512), 256, 0, stream>>>(x, Ue_w, Ue_b, (unsigned*)ue_pk);

    scan_persist<<<NBLK, 1024, 0, stream>>>(
        x, h0, We_p, We_b, ve_w, (const unsigned*)ue_pk,
        (const short8v*)Wt_hi, (const short8v*)Wt_lo, bgv,
        cbuf, hseq, (ull*)At_hi, (ull*)At_lo, bar);

    hipMemsetAsync(lbuf, 0, (size_t)B_ * T_ * 4, stream);
    gemm_l<<<dim3(8, 1024), 256, 0, stream>>>(hseq, Ud_w, Ud_b, vd_w, lbuf);
    final_kernel<<<512, 512, 0, stream>>>(lbuf, hseq, out_w, out_b, out);
}